// Round 1
// baseline (359.965 us; speedup 1.0000x reference)
//
#include <hip/hip_runtime.h>
#include <hip/hip_bf16.h>

#define LN_EPS 1e-5f

typedef float f32x4 __attribute__((ext_vector_type(4)));
typedef short s16x8 __attribute__((ext_vector_type(8)));

__device__ __forceinline__ unsigned short f32_to_bf16(float f) {
  unsigned int u = __float_as_uint(f);
  u += 0x7FFFu + ((u >> 16) & 1u);  // round-nearest-even
  return (unsigned short)(u >> 16);
}

// adj_indices may be int64 (reference asks for it) or int32 (JAX default x64-off).
// If int64 (LE), the high u32 of every qword is 0 for values in [0, N).
__device__ __forceinline__ bool detect_is64(const unsigned int* idx, int E) {
  __shared__ int s_flag;
  if (threadIdx.x == 0) s_flag = 0;
  __syncthreads();
  int nchk = E < 1024 ? E : 1024;
  unsigned int orv = 0u;
  for (int i = threadIdx.x; i < nchk; i += blockDim.x) orv |= idx[2 * i + 1];
  if (orv) atomicOr(&s_flag, 1);
  __syncthreads();
  return s_flag == 0;
}

// ---------- CSR build ----------
__global__ void k_hist(const unsigned int* __restrict__ idx, int E, int* __restrict__ cnt) {
  bool is64 = detect_is64(idx, E);
  int e = blockIdx.x * blockDim.x + threadIdx.x;
  if (e < E) {
    int row = is64 ? (int)idx[2 * e] : ((const int*)idx)[e];
    atomicAdd(&cnt[row], 1);
  }
}

__global__ void k_blocksum(const int* __restrict__ cnt, int N, int* __restrict__ bsum) {
  int i = blockIdx.x * 256 + threadIdx.x;
  int v = (i < N) ? cnt[i] : 0;
#pragma unroll
  for (int d = 1; d < 64; d <<= 1) v += __shfl_xor(v, d);
  __shared__ int s[4];
  if ((threadIdx.x & 63) == 0) s[threadIdx.x >> 6] = v;
  __syncthreads();
  if (threadIdx.x == 0) bsum[blockIdx.x] = s[0] + s[1] + s[2] + s[3];
}

__global__ void k_scan_bsum(int* __restrict__ bsum, int NB) {  // 1 block, 512 thr, NB<=512
  __shared__ int s[512];
  int t = threadIdx.x;
  int v = (t < NB) ? bsum[t] : 0;
  s[t] = v;
  __syncthreads();
  int x = v;
  for (int d = 1; d < 512; d <<= 1) {
    int y = (t >= d) ? s[t - d] : 0;
    __syncthreads();
    x += y;
    s[t] = x;
    __syncthreads();
  }
  if (t < NB) bsum[t] = x - v;  // exclusive block offsets
}

__global__ void k_scan_final(const int* __restrict__ cnt, int N, const int* __restrict__ boff,
                             int* __restrict__ row_ptr, int E) {
  int i = blockIdx.x * 256 + threadIdx.x;
  int v = (i < N) ? cnt[i] : 0;
  int lane = threadIdx.x & 63, wid = threadIdx.x >> 6;
  int x = v;
#pragma unroll
  for (int d = 1; d < 64; d <<= 1) {
    int y = __shfl_up(x, d);
    if (lane >= d) x += y;
  }
  __shared__ int s[4];
  if (lane == 63) s[wid] = x;
  __syncthreads();
  int woff = 0;
  for (int w = 0; w < wid; ++w) woff += s[w];
  if (i < N) row_ptr[i] = x - v + woff + boff[blockIdx.x];
  if (blockIdx.x == 0 && threadIdx.x == 0) row_ptr[N] = E;
}

__global__ void k_scatter(const unsigned int* __restrict__ idx, const float* __restrict__ vals,
                          int E, const int* __restrict__ row_ptr, int* __restrict__ cur,
                          int* __restrict__ col_s, float* __restrict__ val_s) {
  bool is64 = detect_is64(idx, E);
  int e = blockIdx.x * blockDim.x + threadIdx.x;
  if (e < E) {
    int row, col;
    if (is64) { row = (int)idx[2 * e]; col = (int)idx[2 * E + 2 * e]; }
    else      { row = ((const int*)idx)[e]; col = ((const int*)idx)[E + e]; }
    float v = vals[e];
    int pos = row_ptr[row] + atomicAdd(&cur[row], 1);
    col_s[pos] = col;
    val_s[pos] = v;
  }
}

// ---------- dense h = feats @ W, stored bf16 ----------
// block = 256 thr (4 waves), 128 rows/block; wave = 32 rows x 128 cols via 16x16x32 bf16 MFMA.
__global__ __launch_bounds__(256) void k_gemm(const float* __restrict__ feats,
                                              const float* __restrict__ W, int N,
                                              unsigned short* __restrict__ hbf) {
  __shared__ __align__(16) unsigned short Wt[128][136];  // transposed, padded: Wt[col][k]
  int t = threadIdx.x;
  for (int i = t; i < 16384; i += 256) {
    int k = i & 127;       // consecutive t -> consecutive k: conflict-free LDS writes
    int c = i >> 7;
    Wt[c][k] = f32_to_bf16(W[k * 128 + c]);
  }
  __syncthreads();

  int wid = t >> 6, lane = t & 63;
  int rlo = lane & 15, khi = lane >> 4;      // khi in 0..3
  int row0 = blockIdx.x * 128 + wid * 32;

  f32x4 zero = {0.f, 0.f, 0.f, 0.f};
  f32x4 acc[2][8];
#pragma unroll
  for (int m = 0; m < 2; ++m)
#pragma unroll
    for (int n = 0; n < 8; ++n) acc[m][n] = zero;

#pragma unroll
  for (int kb = 0; kb < 4; ++kb) {
    int k0 = kb * 32 + khi * 8;
    s16x8 afr[2];
#pragma unroll
    for (int m = 0; m < 2; ++m) {
      int r = row0 + m * 16 + rlo;
      if (r > N - 1) r = N - 1;
      const float* p = feats + (size_t)r * 128 + k0;
      f32x4 a0 = *(const f32x4*)p;
      f32x4 a1 = *(const f32x4*)(p + 4);
      s16x8 af;
#pragma unroll
      for (int j = 0; j < 4; ++j) af[j] = (short)f32_to_bf16(a0[j]);
#pragma unroll
      for (int j = 0; j < 4; ++j) af[4 + j] = (short)f32_to_bf16(a1[j]);
      afr[m] = af;
    }
#pragma unroll
    for (int n = 0; n < 8; ++n) {
      s16x8 bfr = *(const s16x8*)&Wt[n * 16 + rlo][k0];
#pragma unroll
      for (int m = 0; m < 2; ++m)
        acc[m][n] = __builtin_amdgcn_mfma_f32_16x16x32_bf16(afr[m], bfr, acc[m][n], 0, 0, 0);
    }
  }
  // D layout: col = lane&15, row = (lane>>4)*4 + reg
#pragma unroll
  for (int m = 0; m < 2; ++m)
#pragma unroll
    for (int n = 0; n < 8; ++n)
#pragma unroll
      for (int reg = 0; reg < 4; ++reg) {
        int r = row0 + m * 16 + khi * 4 + reg;
        int c = n * 16 + rlo;
        if (r < N) hbf[(size_t)r * 128 + c] = f32_to_bf16(acc[m][n][reg]);
      }
}

// ---------- SpMM + bias + ELU + LayerNorm, fused; one wave per row ----------
__global__ __launch_bounds__(256) void k_spmm(const unsigned short* __restrict__ hbf,
                                              const int* __restrict__ row_ptr,
                                              const int* __restrict__ col_s,
                                              const float* __restrict__ val_s,
                                              const float* __restrict__ bias,
                                              const float* __restrict__ gamma,
                                              const float* __restrict__ beta,
                                              float* __restrict__ out, int N) {
  int wid = threadIdx.x >> 6, lane = threadIdx.x & 63;
  int r = blockIdx.x * 4 + wid;
  if (r >= N) return;
  int start = row_ptr[r], end = row_ptr[r + 1];
  const unsigned int* h32 = (const unsigned int*)hbf;

  float a0 = 0.f, a1 = 0.f;
  int i = start;
  for (; i + 2 <= end; i += 2) {
    int c0 = col_s[i], c1 = col_s[i + 1];          // wave-uniform -> s_load
    float v0 = val_s[i], v1 = val_s[i + 1];
    unsigned int u0 = h32[(size_t)c0 * 64 + lane]; // 256B coalesced gather
    unsigned int u1 = h32[(size_t)c1 * 64 + lane];
    a0 = fmaf(v0, __uint_as_float(u0 << 16), a0);
    a1 = fmaf(v0, __uint_as_float(u0 & 0xFFFF0000u), a1);
    a0 = fmaf(v1, __uint_as_float(u1 << 16), a0);
    a1 = fmaf(v1, __uint_as_float(u1 & 0xFFFF0000u), a1);
  }
  for (; i < end; ++i) {
    int c = col_s[i];
    float v = val_s[i];
    unsigned int u = h32[(size_t)c * 64 + lane];
    a0 = fmaf(v, __uint_as_float(u << 16), a0);
    a1 = fmaf(v, __uint_as_float(u & 0xFFFF0000u), a1);
  }

  float2 b = ((const float2*)bias)[lane];
  float x0 = a0 + b.x, x1 = a1 + b.y;
  x0 = x0 > 0.f ? x0 : expm1f(x0);
  x1 = x1 > 0.f ? x1 : expm1f(x1);

  float s = x0 + x1;
#pragma unroll
  for (int d = 1; d < 64; d <<= 1) s += __shfl_xor(s, d);
  float mu = s * (1.f / 128.f);
  float d0 = x0 - mu, d1 = x1 - mu;
  float q = d0 * d0 + d1 * d1;
#pragma unroll
  for (int d = 1; d < 64; d <<= 1) q += __shfl_xor(q, d);
  float rstd = rsqrtf(q * (1.f / 128.f) + LN_EPS);

  float2 g = ((const float2*)gamma)[lane];
  float2 be = ((const float2*)beta)[lane];
  float o0 = d0 * rstd * g.x + be.x;
  float o1 = d1 * rstd * g.y + be.y;
  ((float2*)out)[(size_t)r * 64 + lane] = make_float2(o0, o1);
}

extern "C" void kernel_launch(void* const* d_in, const int* in_sizes, int n_in,
                              void* d_out, int out_size, void* d_ws, size_t ws_size,
                              hipStream_t stream) {
  const float* feats = (const float*)d_in[0];
  const unsigned int* idx = (const unsigned int*)d_in[1];
  const float* vals = (const float*)d_in[2];
  const float* W = (const float*)d_in[3];
  const float* bias = (const float*)d_in[4];
  const float* gamma = (const float*)d_in[5];
  const float* beta = (const float*)d_in[6];
  float* out = (float*)d_out;
  int N = in_sizes[0] / 128;
  int E = in_sizes[2];
  (void)n_in; (void)out_size; (void)ws_size;

  char* ws = (char*)d_ws;
  size_t off = 0;
  auto alloc = [&](size_t bytes) {
    char* p = ws + off;
    off += (bytes + 255) & ~(size_t)255;
    return p;
  };
  unsigned short* hbf = (unsigned short*)alloc((size_t)N * 128 * 2);
  int* cnt   = (int*)alloc((size_t)N * 4);
  int* cur   = (int*)alloc((size_t)N * 4);
  int* rowp  = (int*)alloc((size_t)(N + 1) * 4);
  int* bsum  = (int*)alloc(512 * 4);
  int* col_s = (int*)alloc((size_t)E * 4);
  float* val_s = (float*)alloc((size_t)E * 4);

  hipMemsetAsync(cnt, 0, (size_t)N * 4, stream);
  hipMemsetAsync(cur, 0, (size_t)N * 4, stream);

  int NB = (N + 255) / 256;  // 391 for N=100000, must be <=512
  k_hist<<<(E + 255) / 256, 256, 0, stream>>>(idx, E, cnt);
  k_blocksum<<<NB, 256, 0, stream>>>(cnt, N, bsum);
  k_scan_bsum<<<1, 512, 0, stream>>>(bsum, NB);
  k_scan_final<<<NB, 256, 0, stream>>>(cnt, N, bsum, rowp, E);
  k_scatter<<<(E + 255) / 256, 256, 0, stream>>>(idx, vals, E, rowp, cur, col_s, val_s);
  k_gemm<<<(N + 127) / 128, 256, 0, stream>>>(feats, W, N, hbf);
  k_spmm<<<(N + 3) / 4, 256, 0, stream>>>(hbf, rowp, col_s, val_s, bias, gamma, beta, out, N);
}

// Round 3
// 313.855 us; speedup vs baseline: 1.1469x; 1.1469x over previous
//
#include <hip/hip_runtime.h>
#include <hip/hip_bf16.h>

#define LN_EPS 1e-5f

typedef float f32x4 __attribute__((ext_vector_type(4)));
typedef float f32x2 __attribute__((ext_vector_type(2)));
typedef short s16x8 __attribute__((ext_vector_type(8)));

__device__ __forceinline__ unsigned short f32_to_bf16(float f) {
  unsigned int u = __float_as_uint(f);
  u += 0x7FFFu + ((u >> 16) & 1u);  // round-nearest-even
  return (unsigned short)(u >> 16);
}

// ---------- one-shot dtype detect ----------
// adj_indices may be int64 (reference) or int32 (JAX x64-off). If int64 (LE),
// high u32 of each qword is 0 for values in [0,N). Writes flag=1 if int64.
__global__ void k_detect(const unsigned int* __restrict__ idx, int E, int* __restrict__ flag) {
  __shared__ int s_any;
  if (threadIdx.x == 0) s_any = 0;
  __syncthreads();
  int nchk = E < 4096 ? E : 4096;
  unsigned int orv = 0u;
  for (int i = threadIdx.x; i < nchk; i += blockDim.x) orv |= idx[2 * i + 1];
  if (orv) atomicOr(&s_any, 1);
  __syncthreads();
  if (threadIdx.x == 0) *flag = (s_any == 0) ? 1 : 0;
}

// ---------- CSR build ----------
__global__ void k_hist(const unsigned int* __restrict__ idx, int E,
                       const int* __restrict__ flag, int* __restrict__ cnt) {
  bool is64 = (*flag != 0);
  int e = blockIdx.x * blockDim.x + threadIdx.x;
  if (e < E) {
    int row = is64 ? (int)idx[2 * e] : ((const int*)idx)[e];
    atomicAdd(&cnt[row], 1);
  }
}

__global__ void k_blocksum(const int* __restrict__ cnt, int N, int* __restrict__ bsum) {
  int i = blockIdx.x * 256 + threadIdx.x;
  int v = (i < N) ? cnt[i] : 0;
#pragma unroll
  for (int d = 1; d < 64; d <<= 1) v += __shfl_xor(v, d);
  __shared__ int s[4];
  if ((threadIdx.x & 63) == 0) s[threadIdx.x >> 6] = v;
  __syncthreads();
  if (threadIdx.x == 0) bsum[blockIdx.x] = s[0] + s[1] + s[2] + s[3];
}

__global__ void k_scan_bsum(int* __restrict__ bsum, int NB) {  // 1 block, 512 thr, NB<=512
  __shared__ int s[512];
  int t = threadIdx.x;
  int v = (t < NB) ? bsum[t] : 0;
  s[t] = v;
  __syncthreads();
  int x = v;
  for (int d = 1; d < 512; d <<= 1) {
    int y = (t >= d) ? s[t - d] : 0;
    __syncthreads();
    x += y;
    s[t] = x;
    __syncthreads();
  }
  if (t < NB) bsum[t] = x - v;  // exclusive block offsets
}

__global__ void k_scan_final(const int* __restrict__ cnt, int N, const int* __restrict__ boff,
                             int* __restrict__ row_ptr, int E) {
  int i = blockIdx.x * 256 + threadIdx.x;
  int v = (i < N) ? cnt[i] : 0;
  int lane = threadIdx.x & 63, wid = threadIdx.x >> 6;
  int x = v;
#pragma unroll
  for (int d = 1; d < 64; d <<= 1) {
    int y = __shfl_up(x, d);
    if (lane >= d) x += y;
  }
  __shared__ int s[4];
  if (lane == 63) s[wid] = x;
  __syncthreads();
  int woff = 0;
  for (int w = 0; w < wid; ++w) woff += s[w];
  if (i < N) row_ptr[i] = x - v + woff + boff[blockIdx.x];
  if (blockIdx.x == 0 && threadIdx.x == 0) row_ptr[N] = E;
}

// One scattered 8B store per edge (col,val packed) instead of two 4B stores
// into separate arrays: halves distinct-line touches and store transactions.
__global__ void k_scatter(const unsigned int* __restrict__ idx, const float* __restrict__ vals,
                          int E, const int* __restrict__ flag,
                          const int* __restrict__ row_ptr, int* __restrict__ cur,
                          int2* __restrict__ rec) {
  bool is64 = (*flag != 0);
  int e = blockIdx.x * blockDim.x + threadIdx.x;
  if (e < E) {
    int row, col;
    if (is64) { row = (int)idx[2 * e]; col = (int)idx[2 * E + 2 * e]; }
    else      { row = ((const int*)idx)[e]; col = ((const int*)idx)[E + e]; }
    float v = vals[e];
    int pos = row_ptr[row] + atomicAdd(&cur[row], 1);
    rec[pos] = make_int2(col, __float_as_int(v));
  }
}

// ---------- dense h = feats @ W, stored bf16 ----------
__global__ __launch_bounds__(256) void k_gemm(const float* __restrict__ feats,
                                              const float* __restrict__ W, int N,
                                              unsigned short* __restrict__ hbf) {
  __shared__ __align__(16) unsigned short Wt[128][136];  // transposed, padded: Wt[col][k]
  int t = threadIdx.x;
  for (int i = t; i < 16384; i += 256) {
    int k = i & 127;
    int c = i >> 7;
    Wt[c][k] = f32_to_bf16(W[k * 128 + c]);
  }
  __syncthreads();

  int wid = t >> 6, lane = t & 63;
  int rlo = lane & 15, khi = lane >> 4;
  int row0 = blockIdx.x * 128 + wid * 32;

  f32x4 zero = {0.f, 0.f, 0.f, 0.f};
  f32x4 acc[2][8];
#pragma unroll
  for (int m = 0; m < 2; ++m)
#pragma unroll
    for (int n = 0; n < 8; ++n) acc[m][n] = zero;

#pragma unroll
  for (int kb = 0; kb < 4; ++kb) {
    int k0 = kb * 32 + khi * 8;
    s16x8 afr[2];
#pragma unroll
    for (int m = 0; m < 2; ++m) {
      int r = row0 + m * 16 + rlo;
      if (r > N - 1) r = N - 1;
      const float* p = feats + (size_t)r * 128 + k0;
      f32x4 a0 = *(const f32x4*)p;
      f32x4 a1 = *(const f32x4*)(p + 4);
      s16x8 af;
#pragma unroll
      for (int j = 0; j < 4; ++j) af[j] = (short)f32_to_bf16(a0[j]);
#pragma unroll
      for (int j = 0; j < 4; ++j) af[4 + j] = (short)f32_to_bf16(a1[j]);
      afr[m] = af;
    }
#pragma unroll
    for (int n = 0; n < 8; ++n) {
      s16x8 bfr = *(const s16x8*)&Wt[n * 16 + rlo][k0];
#pragma unroll
      for (int m = 0; m < 2; ++m)
        acc[m][n] = __builtin_amdgcn_mfma_f32_16x16x32_bf16(afr[m], bfr, acc[m][n], 0, 0, 0);
    }
  }
  // D layout: col = lane&15, row = (lane>>4)*4 + reg
#pragma unroll
  for (int m = 0; m < 2; ++m)
#pragma unroll
    for (int n = 0; n < 8; ++n)
#pragma unroll
      for (int reg = 0; reg < 4; ++reg) {
        int r = row0 + m * 16 + khi * 4 + reg;
        int c = n * 16 + rlo;
        if (r < N) hbf[(size_t)r * 128 + c] = f32_to_bf16(acc[m][n][reg]);
      }
}

// ---------- SpMM + bias + ELU + LayerNorm, fused; one wave per row ----------
__global__ __launch_bounds__(256) void k_spmm(const unsigned short* __restrict__ hbf,
                                              const int* __restrict__ row_ptr,
                                              const int2* __restrict__ rec,
                                              const float* __restrict__ bias,
                                              const float* __restrict__ gamma,
                                              const float* __restrict__ beta,
                                              float* __restrict__ out, int N) {
  int wid = threadIdx.x >> 6, lane = threadIdx.x & 63;
  int r = blockIdx.x * 4 + wid;
  if (r >= N) return;
  int start = row_ptr[r], end = row_ptr[r + 1];
  const unsigned int* h32 = (const unsigned int*)hbf;

  float a0 = 0.f, a1 = 0.f;
  int i = start;
  // unroll 4: keep 4 outstanding 256B gathers per wave for latency hiding
  for (; i + 4 <= end; i += 4) {
    int2 e0 = rec[i], e1 = rec[i + 1], e2 = rec[i + 2], e3 = rec[i + 3];
    unsigned int u0 = h32[(size_t)e0.x * 64 + lane];
    unsigned int u1 = h32[(size_t)e1.x * 64 + lane];
    unsigned int u2 = h32[(size_t)e2.x * 64 + lane];
    unsigned int u3 = h32[(size_t)e3.x * 64 + lane];
    float v0 = __int_as_float(e0.y), v1 = __int_as_float(e1.y);
    float v2 = __int_as_float(e2.y), v3 = __int_as_float(e3.y);
    a0 = fmaf(v0, __uint_as_float(u0 << 16), a0);
    a1 = fmaf(v0, __uint_as_float(u0 & 0xFFFF0000u), a1);
    a0 = fmaf(v1, __uint_as_float(u1 << 16), a0);
    a1 = fmaf(v1, __uint_as_float(u1 & 0xFFFF0000u), a1);
    a0 = fmaf(v2, __uint_as_float(u2 << 16), a0);
    a1 = fmaf(v2, __uint_as_float(u2 & 0xFFFF0000u), a1);
    a0 = fmaf(v3, __uint_as_float(u3 << 16), a0);
    a1 = fmaf(v3, __uint_as_float(u3 & 0xFFFF0000u), a1);
  }
  for (; i < end; ++i) {
    int2 e = rec[i];
    unsigned int u = h32[(size_t)e.x * 64 + lane];
    float v = __int_as_float(e.y);
    a0 = fmaf(v, __uint_as_float(u << 16), a0);
    a1 = fmaf(v, __uint_as_float(u & 0xFFFF0000u), a1);
  }

  float2 b = ((const float2*)bias)[lane];
  float x0 = a0 + b.x, x1 = a1 + b.y;
  x0 = x0 > 0.f ? x0 : expm1f(x0);
  x1 = x1 > 0.f ? x1 : expm1f(x1);

  float s = x0 + x1;
#pragma unroll
  for (int d = 1; d < 64; d <<= 1) s += __shfl_xor(s, d);
  float mu = s * (1.f / 128.f);
  float d0 = x0 - mu, d1 = x1 - mu;
  float q = d0 * d0 + d1 * d1;
#pragma unroll
  for (int d = 1; d < 64; d <<= 1) q += __shfl_xor(q, d);
  float rstd = rsqrtf(q * (1.f / 128.f) + LN_EPS);

  float2 g = ((const float2*)gamma)[lane];
  float2 be = ((const float2*)beta)[lane];
  f32x2 o;
  o[0] = d0 * rstd * g.x + be.x;
  o[1] = d1 * rstd * g.y + be.y;
  // streaming store: don't evict L2/L3-resident hbf
  __builtin_nontemporal_store(o, (f32x2*)out + (size_t)r * 64 + lane);
}

extern "C" void kernel_launch(void* const* d_in, const int* in_sizes, int n_in,
                              void* d_out, int out_size, void* d_ws, size_t ws_size,
                              hipStream_t stream) {
  const float* feats = (const float*)d_in[0];
  const unsigned int* idx = (const unsigned int*)d_in[1];
  const float* vals = (const float*)d_in[2];
  const float* W = (const float*)d_in[3];
  const float* bias = (const float*)d_in[4];
  const float* gamma = (const float*)d_in[5];
  const float* beta = (const float*)d_in[6];
  float* out = (float*)d_out;
  int N = in_sizes[0] / 128;
  int E = in_sizes[2];
  (void)n_in; (void)out_size; (void)ws_size;

  char* ws = (char*)d_ws;
  size_t off = 0;
  auto alloc = [&](size_t bytes) {
    char* p = ws + off;
    off += (bytes + 255) & ~(size_t)255;
    return p;
  };
  unsigned short* hbf = (unsigned short*)alloc((size_t)N * 128 * 2);
  int* cnt   = (int*)alloc((size_t)N * 4);
  int* cur   = (int*)alloc((size_t)N * 4);
  int* rowp  = (int*)alloc((size_t)(N + 1) * 4);
  int* bsum  = (int*)alloc(512 * 4);
  int* flag  = (int*)alloc(256);
  int2* rec  = (int2*)alloc((size_t)E * 8);

  hipMemsetAsync(cnt, 0, (size_t)N * 4, stream);
  hipMemsetAsync(cur, 0, (size_t)N * 4, stream);

  int NB = (N + 255) / 256;  // 391 for N=100000, must be <=512
  k_detect<<<1, 1024, 0, stream>>>(idx, E, flag);
  k_hist<<<(E + 255) / 256, 256, 0, stream>>>(idx, E, flag, cnt);
  k_blocksum<<<NB, 256, 0, stream>>>(cnt, N, bsum);
  k_scan_bsum<<<1, 512, 0, stream>>>(bsum, NB);
  k_scan_final<<<NB, 256, 0, stream>>>(cnt, N, bsum, rowp, E);
  k_scatter<<<(E + 255) / 256, 256, 0, stream>>>(idx, vals, E, flag, rowp, cur, rec);
  k_gemm<<<(N + 127) / 128, 256, 0, stream>>>(feats, W, N, hbf);
  k_spmm<<<(N + 3) / 4, 256, 0, stream>>>(hbf, rowp, rec, bias, gamma, beta, out, N);
}